// Round 1
// baseline (1175.991 us; speedup 1.0000x reference)
//
#include <hip/hip_runtime.h>

#define TPB 256

// ---- degree: deg[dst[e]] += 1 ----
__global__ __launch_bounds__(TPB) void deg_kernel(const int* __restrict__ dst,
                                                  float* __restrict__ deg, int E) {
    int e = blockIdx.x * TPB + threadIdx.x;
    if (e < E) atomicAdd(&deg[dst[e]], 1.0f);
}

// ---- scatter: agg[dst[e]][c] += feat[src[e]][c], 64 cols, one wave per edge ----
__global__ __launch_bounds__(TPB) void scatter64_kernel(const float* __restrict__ feat,
                                                        const int* __restrict__ src,
                                                        const int* __restrict__ dst,
                                                        float* __restrict__ agg, int E) {
    long long t = (long long)blockIdx.x * TPB + threadIdx.x;
    int e = (int)(t >> 6);
    if (e >= E) return;
    int c = (int)(t & 63);
    int s = src[e], d = dst[e];
    atomicAdd(&agg[d * 64 + c], feat[s * 64 + c]);
}

// ---- y[g][c] = sum_k x[g][k]*W[c][k]; MODE1: += aggr[g][c]/max(deg,1)+bias[c], relu ----
// Block: 64 nodes x 64 cols, 256 threads, 4x4 register tile per thread.
// LDS exactly 64KB; XOR swizzle for conflict-free reads (no room for padding).
template <int MODE>
__global__ __launch_bounds__(TPB) void lin128to64_kernel(
    const float* __restrict__ x, const float* __restrict__ W,
    const float* __restrict__ aggr, const float* __restrict__ deg,
    const float* __restrict__ bias, float* __restrict__ out, int n) {
    __shared__ float Ws[64 * 128];  // Ws[c*128 + (k ^ (c&31))] = W[c][k]
    __shared__ float xs[64 * 128];  // xs[r*128 + (k ^ ((r&3)<<3))] = x[node0+r][k]
    const int tid = threadIdx.x;
    const int node0 = blockIdx.x * 64;

    for (int idx = tid; idx < 64 * 128; idx += TPB) {
        int r = idx >> 7, k = idx & 127;
        Ws[(r << 7) + (k ^ (r & 31))] = W[idx];
    }
    for (int idx = tid; idx < 64 * 128; idx += TPB) {
        int r = idx >> 7, k = idx & 127;
        int g = node0 + r;
        xs[(r << 7) + (k ^ ((r & 3) << 3))] = (g < n) ? x[(long long)g * 128 + k] : 0.0f;
    }
    __syncthreads();

    const int cg = tid & 15;   // col group: cols cg + 16j
    const int ng = tid >> 4;   // node group: nodes ng + 16i
    float acc[4][4];
#pragma unroll
    for (int i = 0; i < 4; ++i)
#pragma unroll
        for (int j = 0; j < 4; ++j) acc[i][j] = 0.0f;

    const int xsw = (ng & 3) << 3;
    int wbase[4], wsw[4], xbase[4];
#pragma unroll
    for (int j = 0; j < 4; ++j) {
        int c = cg + 16 * j;
        wbase[j] = c << 7;
        wsw[j] = c & 31;
    }
#pragma unroll
    for (int i = 0; i < 4; ++i) xbase[i] = (ng + 16 * i) << 7;

#pragma unroll 4
    for (int k = 0; k < 128; ++k) {
        float xv[4], wv[4];
        int kx = k ^ xsw;
#pragma unroll
        for (int i = 0; i < 4; ++i) xv[i] = xs[xbase[i] + kx];
#pragma unroll
        for (int j = 0; j < 4; ++j) wv[j] = Ws[wbase[j] + (k ^ wsw[j])];
#pragma unroll
        for (int i = 0; i < 4; ++i)
#pragma unroll
            for (int j = 0; j < 4; ++j) acc[i][j] += xv[i] * wv[j];
    }

#pragma unroll
    for (int i = 0; i < 4; ++i) {
        int g = node0 + ng + 16 * i;
        if (g >= n) continue;
        float inv = 0.0f;
        if (MODE == 1) inv = 1.0f / fmaxf(deg[g], 1.0f);
#pragma unroll
        for (int j = 0; j < 4; ++j) {
            int c = cg + 16 * j;
            float v = acc[i][j];
            if (MODE == 1) {
                v += aggr[g * 64 + c] * inv + bias[c];
                v = fmaxf(v, 0.0f);
            }
            out[g * 64 + c] = v;
        }
    }
}

// ---- out[g][C] = sum_k am[g][k]*Wl[C][k] + sum_k h[g][k]*Wr[C][k] + b[C] ----
// am = agg2/max(deg,1). Block: 64 nodes x 64 cols (gridDim.y picks col half).
// Four 16KB LDS buffers = exactly 64KB.
__global__ __launch_bounds__(TPB) void out_kernel(
    const float* __restrict__ agg2, const float* __restrict__ h,
    const float* __restrict__ deg, const float* __restrict__ Wl,
    const float* __restrict__ Wr, const float* __restrict__ bias,
    float* __restrict__ out, int n) {
    __shared__ float Wls[64 * 64];  // Wls[c*64 + (k ^ (c&31))] = Wl[chalf+c][k]
    __shared__ float Wrs[64 * 64];
    __shared__ float ams[64 * 64];  // ams[r*64 + k] = agg2[node0+r][k]/max(deg,1)
    __shared__ float hhs[64 * 64];
    const int tid = threadIdx.x;
    const int node0 = blockIdx.x * 64;
    const int chalf = blockIdx.y * 64;

    for (int idx = tid; idx < 64 * 64; idx += TPB) {
        int c = idx >> 6, k = idx & 63;
        int sw = (c << 6) + (k ^ (c & 31));
        Wls[sw] = Wl[(chalf + c) * 64 + k];
        Wrs[sw] = Wr[(chalf + c) * 64 + k];
    }
    for (int idx = tid; idx < 64 * 64; idx += TPB) {
        int r = idx >> 6, k = idx & 63;
        int g = node0 + r;
        float av = 0.0f, hv = 0.0f;
        if (g < n) {
            float inv = 1.0f / fmaxf(deg[g], 1.0f);
            av = agg2[g * 64 + k] * inv;
            hv = h[g * 64 + k];
        }
        ams[(r << 6) + k] = av;
        hhs[(r << 6) + k] = hv;
    }
    __syncthreads();

    const int cg = tid & 31;  // cols cg and cg+32 (local)
    const int ng = tid >> 5;  // nodes ng + 8i, i=0..7
    float acc[8][2];
#pragma unroll
    for (int i = 0; i < 8; ++i) { acc[i][0] = 0.0f; acc[i][1] = 0.0f; }
    const int wb0 = cg << 6;
    const int wb1 = (cg + 32) << 6;

#pragma unroll 4
    for (int k = 0; k < 64; ++k) {
        int kk = k ^ cg;  // (cg+32)&31 == cg, same swizzle for both cols
        float wl0 = Wls[wb0 + kk], wl1 = Wls[wb1 + kk];
        float wr0 = Wrs[wb0 + kk], wr1 = Wrs[wb1 + kk];
#pragma unroll
        for (int i = 0; i < 8; ++i) {
            int r = ng + 8 * i;
            float av = ams[(r << 6) + k];
            float hv = hhs[(r << 6) + k];
            acc[i][0] += av * wl0 + hv * wr0;
            acc[i][1] += av * wl1 + hv * wr1;
        }
    }

#pragma unroll
    for (int i = 0; i < 8; ++i) {
        int g = node0 + ng + 8 * i;
        if (g >= n) continue;
        long long base = (long long)g * 128 + chalf;
        out[base + cg] = acc[i][0] + bias[chalf + cg];
        out[base + cg + 32] = acc[i][1] + bias[chalf + cg + 32];
    }
}

extern "C" void kernel_launch(void* const* d_in, const int* in_sizes, int n_in,
                              void* d_out, int out_size, void* d_ws, size_t ws_size,
                              hipStream_t stream) {
    const float* x = (const float*)d_in[0];
    const int* ei = (const int*)d_in[1];
    const float* Wl1 = (const float*)d_in[2];
    const float* Wr1 = (const float*)d_in[3];
    const float* b1 = (const float*)d_in[4];
    const float* Wl2 = (const float*)d_in[5];
    const float* Wr2 = (const float*)d_in[6];
    const float* b2 = (const float*)d_in[7];
    float* out = (float*)d_out;

    const int n = in_sizes[0] / 128;   // 100000
    const int E = in_sizes[1] / 2;     // 1600000
    const int* src = ei;
    const int* dst = ei + E;

    // workspace layout (floats): deg[n] | bufA[n*64] | bufB[n*64] | bufC[n*64]
    float* ws = (float*)d_ws;
    float* deg = ws;
    float* bufA = ws + ((n + 63) & ~63);        // y1, later agg2
    float* bufB = bufA + (size_t)n * 64;        // agg1
    float* bufC = bufB + (size_t)n * 64;        // h

    hipMemsetAsync(deg, 0, (size_t)n * sizeof(float), stream);
    hipMemsetAsync(bufB, 0, (size_t)n * 64 * sizeof(float), stream);

    deg_kernel<<<(E + TPB - 1) / TPB, TPB, 0, stream>>>(dst, deg, E);

    int gblocks = (n + 63) / 64;
    // y1 = x @ W_l1.T
    lin128to64_kernel<0><<<gblocks, TPB, 0, stream>>>(x, Wl1, nullptr, nullptr, nullptr, bufA, n);

    long long sthreads = (long long)E * 64;
    int sblocks = (int)((sthreads + TPB - 1) / TPB);
    // agg1[dst] += y1[src]
    scatter64_kernel<<<sblocks, TPB, 0, stream>>>(bufA, src, dst, bufB, E);

    // h = relu(agg1/deg + b1 + x @ W_r1.T)
    lin128to64_kernel<1><<<gblocks, TPB, 0, stream>>>(x, Wr1, bufB, deg, b1, bufC, n);

    hipMemsetAsync(bufA, 0, (size_t)n * 64 * sizeof(float), stream);
    // agg2[dst] += h[src]
    scatter64_kernel<<<sblocks, TPB, 0, stream>>>(bufC, src, dst, bufA, E);

    // out = (agg2/deg) @ W_l2.T + b2 + h @ W_r2.T
    dim3 og(gblocks, 2);
    out_kernel<<<og, TPB, 0, stream>>>(bufA, bufC, deg, Wl2, Wr2, b2, out, n);
}

// Round 2
// 693.610 us; speedup vs baseline: 1.6955x; 1.6955x over previous
//
#include <hip/hip_runtime.h>

#define TPB 256

// ================= CSR build =================

__global__ __launch_bounds__(TPB) void hist_kernel(const int* __restrict__ dst,
                                                   int* __restrict__ cnt, int E) {
    int e = blockIdx.x * TPB + threadIdx.x;
    if (e < E) atomicAdd(&cnt[dst[e]], 1);
}

// per-block (1024-elem) exclusive scan of cnt -> rs, block totals -> bsum
__global__ __launch_bounds__(TPB) void scanA_kernel(const int* __restrict__ cnt,
                                                    int* __restrict__ rs,
                                                    int* __restrict__ bsum, int n) {
    __shared__ int lds[TPB];
    const int t = threadIdx.x;
    const int base = blockIdx.x * 1024 + t * 4;
    int v[4], s = 0;
#pragma unroll
    for (int i = 0; i < 4; ++i) {
        int idx = base + i;
        v[i] = (idx < n) ? cnt[idx] : 0;
        s += v[i];
    }
    lds[t] = s;
    __syncthreads();
    for (int off = 1; off < TPB; off <<= 1) {
        int add = (t >= off) ? lds[t - off] : 0;
        __syncthreads();
        lds[t] += add;
        __syncthreads();
    }
    int excl = lds[t] - s;
    int run = excl;
#pragma unroll
    for (int i = 0; i < 4; ++i) {
        int idx = base + i;
        if (idx < n) rs[idx] = run;
        run += v[i];
    }
    if (t == 0) bsum[blockIdx.x] = lds[TPB - 1];
}

// single block: exclusive scan of bsum (nb <= 256); also set rs[n] = E
__global__ __launch_bounds__(TPB) void scanB_kernel(int* __restrict__ bsum, int nb,
                                                    int* __restrict__ rs, int n, int E) {
    __shared__ int lds[TPB];
    const int t = threadIdx.x;
    int s = (t < nb) ? bsum[t] : 0;
    lds[t] = s;
    __syncthreads();
    for (int off = 1; off < TPB; off <<= 1) {
        int add = (t >= off) ? lds[t - off] : 0;
        __syncthreads();
        lds[t] += add;
        __syncthreads();
    }
    if (t < nb) bsum[t] = lds[t] - s;
    if (t == 0) rs[n] = E;
}

// add block offsets; also init cursor (aliases cnt array) = row start
__global__ __launch_bounds__(TPB) void scanC_kernel(int* __restrict__ rs,
                                                    const int* __restrict__ bsum,
                                                    int* __restrict__ cursor, int n) {
    int idx = blockIdx.x * TPB + threadIdx.x;
    if (idx < n) {
        int v = rs[idx] + bsum[idx >> 10];
        rs[idx] = v;
        cursor[idx] = v;
    }
}

__global__ __launch_bounds__(TPB) void fill_kernel(const int* __restrict__ src,
                                                   const int* __restrict__ dst,
                                                   int* __restrict__ cursor,
                                                   int* __restrict__ perm, int E) {
    int e = blockIdx.x * TPB + threadIdx.x;
    if (e < E) {
        int p = atomicAdd(&cursor[dst[e]], 1);
        perm[p] = src[e];
    }
}

// ====== mean aggregation: one wave per dst node, gather via CSR ======
// lane = q*16 + cl; quad q handles edge slot e+q, lanes cl cover 64 cols as float4.
__global__ __launch_bounds__(TPB) void csr_mean_kernel(const float* __restrict__ feat,
                                                       const int* __restrict__ rs,
                                                       const int* __restrict__ perm,
                                                       float* __restrict__ outm, int n) {
    int w = (int)((blockIdx.x * (long long)TPB + threadIdx.x) >> 6);
    if (w >= n) return;
    const int lane = threadIdx.x & 63;
    const int q = lane >> 4;
    const int cc = (lane & 15) << 2;
    const int beg = rs[w], end = rs[w + 1];
    float4 acc = make_float4(0.f, 0.f, 0.f, 0.f);
    for (int e = beg; e < end; e += 4) {
        int ee = e + q;
        if (ee < end) {
            int s = perm[ee];
            float4 v = *(const float4*)(feat + (long long)s * 64 + cc);
            acc.x += v.x; acc.y += v.y; acc.z += v.z; acc.w += v.w;
        }
    }
#pragma unroll
    for (int off = 16; off < 64; off <<= 1) {
        acc.x += __shfl_xor(acc.x, off, 64);
        acc.y += __shfl_xor(acc.y, off, 64);
        acc.z += __shfl_xor(acc.z, off, 64);
        acc.w += __shfl_xor(acc.w, off, 64);
    }
    if (lane < 16) {
        float d = (float)(end - beg);
        float inv = d > 0.f ? 1.f / d : 0.f;
        acc.x *= inv; acc.y *= inv; acc.z *= inv; acc.w *= inv;
        *(float4*)(outm + (long long)w * 64 + cc) = acc;
    }
}

// ---- y[g][c] = sum_k x[g][k]*W[c][k]; MODE1: += aggr[g][c] (pre-meaned) + bias[c], relu ----
// Block: 64 nodes x 64 cols, 256 threads, 4x4 register tile per thread.
// LDS exactly 64KB; XOR swizzle for conflict-free reads (no room for padding).
template <int MODE>
__global__ __launch_bounds__(TPB) void lin128to64_kernel(
    const float* __restrict__ x, const float* __restrict__ W,
    const float* __restrict__ aggr, const float* __restrict__ bias,
    float* __restrict__ out, int n) {
    __shared__ float Ws[64 * 128];  // Ws[c*128 + (k ^ (c&31))] = W[c][k]
    __shared__ float xs[64 * 128];  // xs[r*128 + (k ^ ((r&3)<<3))] = x[node0+r][k]
    const int tid = threadIdx.x;
    const int node0 = blockIdx.x * 64;

    for (int idx = tid; idx < 64 * 128; idx += TPB) {
        int r = idx >> 7, k = idx & 127;
        Ws[(r << 7) + (k ^ (r & 31))] = W[idx];
    }
    for (int idx = tid; idx < 64 * 128; idx += TPB) {
        int r = idx >> 7, k = idx & 127;
        int g = node0 + r;
        xs[(r << 7) + (k ^ ((r & 3) << 3))] = (g < n) ? x[(long long)g * 128 + k] : 0.0f;
    }
    __syncthreads();

    const int cg = tid & 15;   // col group: cols cg + 16j
    const int ng = tid >> 4;   // node group: nodes ng + 16i
    float acc[4][4];
#pragma unroll
    for (int i = 0; i < 4; ++i)
#pragma unroll
        for (int j = 0; j < 4; ++j) acc[i][j] = 0.0f;

    const int xsw = (ng & 3) << 3;
    int wbase[4], wsw[4], xbase[4];
#pragma unroll
    for (int j = 0; j < 4; ++j) {
        int c = cg + 16 * j;
        wbase[j] = c << 7;
        wsw[j] = c & 31;
    }
#pragma unroll
    for (int i = 0; i < 4; ++i) xbase[i] = (ng + 16 * i) << 7;

#pragma unroll 4
    for (int k = 0; k < 128; ++k) {
        float xv[4], wv[4];
        int kx = k ^ xsw;
#pragma unroll
        for (int i = 0; i < 4; ++i) xv[i] = xs[xbase[i] + kx];
#pragma unroll
        for (int j = 0; j < 4; ++j) wv[j] = Ws[wbase[j] + (k ^ wsw[j])];
#pragma unroll
        for (int i = 0; i < 4; ++i)
#pragma unroll
            for (int j = 0; j < 4; ++j) acc[i][j] += xv[i] * wv[j];
    }

#pragma unroll
    for (int i = 0; i < 4; ++i) {
        int g = node0 + ng + 16 * i;
        if (g >= n) continue;
#pragma unroll
        for (int j = 0; j < 4; ++j) {
            int c = cg + 16 * j;
            float v = acc[i][j];
            if (MODE == 1) {
                v += aggr[g * 64 + c] + bias[c];
                v = fmaxf(v, 0.0f);
            }
            out[g * 64 + c] = v;
        }
    }
}

// ---- out[g][C] = sum_k m2[g][k]*Wl[C][k] + sum_k h[g][k]*Wr[C][k] + b[C] ----
// m2 already meaned. Block: 64 nodes x 64 cols (gridDim.y picks col half).
__global__ __launch_bounds__(TPB) void out_kernel(
    const float* __restrict__ m2, const float* __restrict__ h,
    const float* __restrict__ Wl, const float* __restrict__ Wr,
    const float* __restrict__ bias, float* __restrict__ out, int n) {
    __shared__ float Wls[64 * 64];  // Wls[c*64 + (k ^ (c&31))] = Wl[chalf+c][k]
    __shared__ float Wrs[64 * 64];
    __shared__ float ams[64 * 64];  // ams[r*64 + k] = m2[node0+r][k]
    __shared__ float hhs[64 * 64];
    const int tid = threadIdx.x;
    const int node0 = blockIdx.x * 64;
    const int chalf = blockIdx.y * 64;

    for (int idx = tid; idx < 64 * 64; idx += TPB) {
        int c = idx >> 6, k = idx & 63;
        int sw = (c << 6) + (k ^ (c & 31));
        Wls[sw] = Wl[(chalf + c) * 64 + k];
        Wrs[sw] = Wr[(chalf + c) * 64 + k];
    }
    for (int idx = tid; idx < 64 * 64; idx += TPB) {
        int r = idx >> 6, k = idx & 63;
        int g = node0 + r;
        float av = 0.0f, hv = 0.0f;
        if (g < n) {
            av = m2[g * 64 + k];
            hv = h[g * 64 + k];
        }
        ams[(r << 6) + k] = av;
        hhs[(r << 6) + k] = hv;
    }
    __syncthreads();

    const int cg = tid & 31;  // cols cg and cg+32 (local)
    const int ng = tid >> 5;  // nodes ng + 8i, i=0..7
    float acc[8][2];
#pragma unroll
    for (int i = 0; i < 8; ++i) { acc[i][0] = 0.0f; acc[i][1] = 0.0f; }
    const int wb0 = cg << 6;
    const int wb1 = (cg + 32) << 6;

#pragma unroll 4
    for (int k = 0; k < 64; ++k) {
        int kk = k ^ cg;  // (cg+32)&31 == cg, same swizzle for both cols
        float wl0 = Wls[wb0 + kk], wl1 = Wls[wb1 + kk];
        float wr0 = Wrs[wb0 + kk], wr1 = Wrs[wb1 + kk];
#pragma unroll
        for (int i = 0; i < 8; ++i) {
            int r = ng + 8 * i;
            float av = ams[(r << 6) + k];
            float hv = hhs[(r << 6) + k];
            acc[i][0] += av * wl0 + hv * wr0;
            acc[i][1] += av * wl1 + hv * wr1;
        }
    }

#pragma unroll
    for (int i = 0; i < 8; ++i) {
        int g = node0 + ng + 8 * i;
        if (g >= n) continue;
        long long base = (long long)g * 128 + chalf;
        out[base + cg] = acc[i][0] + bias[chalf + cg];
        out[base + cg + 32] = acc[i][1] + bias[chalf + cg + 32];
    }
}

extern "C" void kernel_launch(void* const* d_in, const int* in_sizes, int n_in,
                              void* d_out, int out_size, void* d_ws, size_t ws_size,
                              hipStream_t stream) {
    const float* x = (const float*)d_in[0];
    const int* ei = (const int*)d_in[1];
    const float* Wl1 = (const float*)d_in[2];
    const float* Wr1 = (const float*)d_in[3];
    const float* b1 = (const float*)d_in[4];
    const float* Wl2 = (const float*)d_in[5];
    const float* Wr2 = (const float*)d_in[6];
    const float* b2 = (const float*)d_in[7];
    float* out = (float*)d_out;

    const int n = in_sizes[0] / 128;   // 100000
    const int E = in_sizes[1] / 2;     // 1600000
    const int* src = ei;
    const int* dst = ei + E;

    // workspace layout (4B elems, 64-elem aligned):
    // cnt/cursor[n] | rs[n+1] | bsum[256] | perm[E] | bufA[n*64] | bufB[n*64] | bufC[n*64]
    char* ws = (char*)d_ws;
    auto A = [](size_t x) { return (x + 63) & ~(size_t)63; };
    int* cnt = (int*)ws;                         size_t o = A(n);
    int* rs = (int*)ws + o;                      o += A(n + 1);
    int* bsum = (int*)ws + o;                    o += 256;
    int* perm = (int*)ws + o;                    o += A(E);
    float* bufA = (float*)ws + o;                o += (size_t)n * 64;
    float* bufB = (float*)ws + o;                o += (size_t)n * 64;
    float* bufC = (float*)ws + o;

    // ---- CSR build (by dst) ----
    hipMemsetAsync(cnt, 0, (size_t)n * sizeof(int), stream);
    hist_kernel<<<(E + TPB - 1) / TPB, TPB, 0, stream>>>(dst, cnt, E);
    const int nb = (n + 1023) / 1024;  // 98
    scanA_kernel<<<nb, TPB, 0, stream>>>(cnt, rs, bsum, n);
    scanB_kernel<<<1, TPB, 0, stream>>>(bsum, nb, rs, n, E);
    scanC_kernel<<<(n + TPB - 1) / TPB, TPB, 0, stream>>>(rs, bsum, cnt, n);
    fill_kernel<<<(E + TPB - 1) / TPB, TPB, 0, stream>>>(src, dst, cnt, perm, E);

    const int gblocks = (n + 63) / 64;
    const int mblocks = (int)(((long long)n * 64 + TPB - 1) / TPB);

    // y1 = x @ W_l1.T
    lin128to64_kernel<0><<<gblocks, TPB, 0, stream>>>(x, Wl1, nullptr, nullptr, bufA, n);
    // mean1 = csr_mean(y1)
    csr_mean_kernel<<<mblocks, TPB, 0, stream>>>(bufA, rs, perm, bufB, n);
    // h = relu(mean1 + b1 + x @ W_r1.T)
    lin128to64_kernel<1><<<gblocks, TPB, 0, stream>>>(x, Wr1, bufB, b1, bufC, n);
    // mean2 = csr_mean(h)
    csr_mean_kernel<<<mblocks, TPB, 0, stream>>>(bufC, rs, perm, bufA, n);
    // out = mean2 @ W_l2.T + b2 + h @ W_r2.T
    dim3 og(gblocks, 2);
    out_kernel<<<og, TPB, 0, stream>>>(bufA, bufC, Wl2, Wr2, b2, out, n);
}